// Round 12
// baseline (3876.284 us; speedup 1.0000x reference)
//
#include <hip/hip_runtime.h>
#include <math.h>

constexpr int nB = 64, nS = 256, nAc = 256, nH = 512, nG = 2048;
constexpr int nWD = 320, nNA = 75, nLB = 48, nFH = 2560;
constexpr int BH = nB * nH; // 32768

typedef _Float16 h16;
typedef _Float16 h16x8 __attribute__((ext_vector_type(8)));
typedef _Float16 h16x4 __attribute__((ext_vector_type(4)));
typedef _Float16 h16x2 __attribute__((ext_vector_type(2)));
typedef float f32x4 __attribute__((ext_vector_type(4)));
typedef unsigned long long u64t;

__device__ __forceinline__ float sigf(float x) { return 1.0f / (1.0f + __expf(-x)); }

#if __has_builtin(__builtin_amdgcn_fdot2)
#define FDOT2(a, b, c) __builtin_amdgcn_fdot2((a), (b), (c), false)
#else
__device__ __forceinline__ float FDOT2(h16x2 a, h16x2 b, float c) {
    return c + (float)a[0] * (float)b[0] + (float)a[1] * (float)b[1];
}
#endif

#define PINV(x) asm volatile("" : "+v"(x))

// ---------------- init: zero hsrec prefix + transport rings + counters ----------------
__global__ void init_k(h16* __restrict__ hsrec, int* __restrict__ counts, int* __restrict__ fill,
                       u64t* __restrict__ hbuf, u64t* __restrict__ spbuf, u64t* __restrict__ apbuf,
                       u64t* __restrict__ tsbuf, u64t* __restrict__ x2buf)
{
    int i = blockIdx.x * 256 + threadIdx.x;   // grid 256x256 = 65536
    if (i < 2 * BH) hsrec[i] = (h16)0.0f;
    if (i < 32768) { hbuf[i] = 0; spbuf[i] = 0; apbuf[i] = 0; }
    tsbuf[i] = 0;                             // 4 x 16384
    #pragma unroll
    for (int j = 0; j < 8; ++j) x2buf[(size_t)j * 65536 + i] = 0;   // 8 x 65536
    if (i < nLB) { counts[i] = 0; fill[i] = 0; }
}

// ---------------- generic fp32 -> fp16 conversion ----------------
__global__ __launch_bounds__(256)
void cvt_k(const float* __restrict__ src, h16* __restrict__ dst, int n4)
{
    const int i = blockIdx.x * 256 + threadIdx.x;
    if (i < n4) {
        const float4 a = ((const float4*)src)[i];
        h16x4 v; v[0]=(h16)a.x; v[1]=(h16)a.y; v[2]=(h16)a.z; v[3]=(h16)a.w;
        ((h16x4*)dst)[i] = v;
    }
}

// ---------------- embedding gather -> tok fp16 [b][s][0:320] ----------------
__global__ __launch_bounds__(64)
void embed_k(const int* __restrict__ tokb, const int* __restrict__ posb,
             const float* __restrict__ wemb, const float* __restrict__ pemb,
             h16* __restrict__ tok)
{
    const int r = blockIdx.x;            // b*nS + s
    const int tid = threadIdx.x;
    const int tk = tokb[r], pp = posb[r];
    h16x8* d = (h16x8*)(tok + (size_t)r * nWD);
    if (tid < 32) {
        const float4* sw = (const float4*)(wemb + (size_t)tk * 256);
        const float4 a = sw[2 * tid], b = sw[2 * tid + 1];
        h16x8 o;
        o[0]=(h16)a.x; o[1]=(h16)a.y; o[2]=(h16)a.z; o[3]=(h16)a.w;
        o[4]=(h16)b.x; o[5]=(h16)b.y; o[6]=(h16)b.z; o[7]=(h16)b.w;
        d[tid] = o;
    } else if (tid < 40) {
        const int q = tid - 32;
        const float4* sp = (const float4*)(pemb + (size_t)pp * 64);
        const float4 a = sp[2 * q], b = sp[2 * q + 1];
        h16x8 o;
        o[0]=(h16)a.x; o[1]=(h16)a.y; o[2]=(h16)a.z; o[3]=(h16)a.w;
        o[4]=(h16)b.x; o[5]=(h16)b.y; o[6]=(h16)b.z; o[7]=(h16)b.w;
        d[32 + q] = o;
    }
}

// ---------------- action-gate table: acTab[a][j] = aemb[a]·aWih[j] + ab[j] ----------------
__global__ __launch_bounds__(256)
void actab_k(const float* __restrict__ aemb, const float* __restrict__ aWih,
             const float* __restrict__ ab, float* __restrict__ acTab)
{
    const int a = blockIdx.x;            // 0..74
    __shared__ float ae[64];
    const int tid = threadIdx.x;
    if (tid < 64) ae[tid] = aemb[a * 64 + tid];
    __syncthreads();
    for (int j = tid; j < nG; j += 256) {
        const float* wr = aWih + (size_t)j * 64;
        float s = ab[j];
        #pragma unroll
        for (int k = 0; k < 64; k += 4) {
            const float4 w = *(const float4*)(wr + k);
            s = fmaf(w.x, ae[k], s);     s = fmaf(w.y, ae[k + 1], s);
            s = fmaf(w.z, ae[k + 2], s); s = fmaf(w.w, ae[k + 3], s);
        }
        acTab[(size_t)a * nG + j] = s;
    }
}

// =============== MFMA fp16 GEMM: C[r][n] = Arow(r)·Wm[n][:] + bias[n] ===============
template<int MODE, bool RELU>
__global__ __launch_bounds__(256)
void mgemm_k(const h16* __restrict__ Wm, const float* __restrict__ bias,
             const h16* __restrict__ A0, const h16* __restrict__ A1,
             const h16* __restrict__ A2, h16* __restrict__ C, int Ktot, int ldC)
{
    const int bm = blockIdx.x << 6, bn = blockIdx.y << 6;
    const int tid = threadIdx.x;
    const int lane = tid & 63, wave = tid >> 6;
    const int wr = wave >> 1, wc = wave & 1;
    __shared__ __align__(16) h16 As[64][40];
    __shared__ __align__(16) h16 Ws[64][40];
    const int srow = tid >> 2, sk = (tid & 3) << 3;
    const int r3 = bm + srow;
    const h16* arow = nullptr;
    if (MODE == 0) { const int b = r3 & 63, s = r3 >> 6; arow = A0 + ((size_t)b * nS + s) * nWD; }
    if (MODE == 5) { arow = A0 + (size_t)r3 * nWD; }
    const h16* wrow = Wm + (size_t)(bn + srow) * Ktot;
    f32x4 acc[2][2] = {};
    for (int k0 = 0; k0 < Ktot; k0 += 32) {
        h16x8 av, wv;
        if (MODE == 3) {
            const int k = k0 + sk;
            const int p = k >> 9;
            const h16* base = (p == 0) ? A0 + 2 * BH : (p == 1) ? A0 + BH
                            : (p == 2) ? A0 : (p == 3) ? A1 : A2;
            av = *(const h16x8*)(base + (size_t)r3 * nH + (k & 511));
        } else {
            av = *(const h16x8*)(arow + k0 + sk);
        }
        wv = *(const h16x8*)(wrow + k0 + sk);
        __syncthreads();
        *(h16x8*)(&As[srow][sk]) = av;
        *(h16x8*)(&Ws[srow][sk]) = wv;
        __syncthreads();
        const int fk = (lane >> 4) << 3;
        const int fr = lane & 15;
        h16x8 af0 = *(const h16x8*)(&As[(wr << 5) + fr][fk]);
        h16x8 af1 = *(const h16x8*)(&As[(wr << 5) + 16 + fr][fk]);
        h16x8 bf0 = *(const h16x8*)(&Ws[(wc << 5) + fr][fk]);
        h16x8 bf1 = *(const h16x8*)(&Ws[(wc << 5) + 16 + fr][fk]);
        acc[0][0] = __builtin_amdgcn_mfma_f32_16x16x32_f16(af0, bf0, acc[0][0], 0, 0, 0);
        acc[0][1] = __builtin_amdgcn_mfma_f32_16x16x32_f16(af0, bf1, acc[0][1], 0, 0, 0);
        acc[1][0] = __builtin_amdgcn_mfma_f32_16x16x32_f16(af1, bf0, acc[1][0], 0, 0, 0);
        acc[1][1] = __builtin_amdgcn_mfma_f32_16x16x32_f16(af1, bf1, acc[1][1], 0, 0, 0);
    }
    #pragma unroll
    for (int mi = 0; mi < 2; ++mi) {
        #pragma unroll
        for (int ni = 0; ni < 2; ++ni) {
            const int col = bn + (wc << 5) + (ni << 4) + (lane & 15);
            const float bs = bias[col];
            #pragma unroll
            for (int rg = 0; rg < 4; ++rg) {
                const int row = bm + (wr << 5) + (mi << 4) + ((lane >> 4) << 2) + rg;
                float x = acc[mi][ni][rg] + bs;
                if (RELU) x = fmaxf(x, 0.0f);
                C[(size_t)row * ldC + col] = (h16)x;
            }
        }
    }
}

// ---------------- label sort for red_W batched GEMM ----------------
__global__ void hist_k(const int* __restrict__ actb, int* __restrict__ lab, int* __restrict__ counts)
{
    const int r = blockIdx.x * 256 + threadIdx.x;
    const int t = r >> 6, b = r & 63;
    const int a = actb[b * nAc + t];
    const int l = a % nLB;
    lab[r] = l;
    atomicAdd(&counts[l], 1);
}

__global__ void tiles_k(const int* __restrict__ counts, int* __restrict__ offs,
                        int* __restrict__ tl_lab, int* __restrict__ tl_start,
                        int* __restrict__ tl_cnt, int* __restrict__ ntiles)
{
    if (blockIdx.x == 0 && threadIdx.x == 0) {
        int o = 0, nt = 0;
        for (int l = 0; l < nLB; ++l) {
            offs[l] = o;
            const int c = counts[l];
            for (int s0 = 0; s0 < c; s0 += 64) {
                tl_lab[nt] = l; tl_start[nt] = o + s0; tl_cnt[nt] = min(64, c - s0); ++nt;
            }
            o += c;
        }
        offs[nLB] = o;
        ntiles[0] = nt;
    }
}

__global__ void scatter_k(const int* __restrict__ lab, const int* __restrict__ offs,
                          int* __restrict__ fill, int* __restrict__ idx)
{
    const int r = blockIdx.x * 256 + threadIdx.x;
    const int l = lab[r];
    const int pos = offs[l] + atomicAdd(&fill[l], 1);
    idx[pos] = r;
}

// composed[r][i] = tanh( pair(r)·red_W[l][i][:] + red_b[l][i] ), rows grouped by label
__global__ __launch_bounds__(256)
void comp_gemm_k(const h16* __restrict__ tok, const float* __restrict__ redW,
                 const float* __restrict__ redb, const int* __restrict__ idx,
                 const int* __restrict__ tl_lab, const int* __restrict__ tl_start,
                 const int* __restrict__ tl_cnt, const int* __restrict__ ntiles,
                 h16* __restrict__ comp)
{
    const int tile = blockIdx.x;
    if (tile >= ntiles[0]) return;
    const int cn0 = blockIdx.y << 6;
    const int l = tl_lab[tile], rst = tl_start[tile], mrows = tl_cnt[tile];
    __shared__ int rows_s[64];
    __shared__ __align__(16) float As[16][68];
    __shared__ __align__(16) float Ws[16][68];
    const int tid = threadIdx.x;
    if (tid < 64) rows_s[tid] = (tid < mrows) ? idx[rst + tid] : -1;
    __syncthreads();
    const int alm = tid >> 1, alk = (tid & 1) << 3;
    const int wlm = tid >> 2, wlk = (tid & 3) << 2;
    const int trow = tid >> 4, tcol = tid & 15;
    const int rm = (tid < 128) ? rows_s[alm] : -1;
    const h16* arow0 = tok;
    const h16* arow1 = tok;
    if (rm >= 0) {
        const int b = rm & 63, t = rm >> 6;
        arow0 = tok + ((size_t)b * nS + t) * nWD;
        arow1 = tok + ((size_t)b * nS + max(t - 1, 0)) * nWD;
    }
    const float* wrow = redW + (size_t)l * (320 * 640) + (size_t)(cn0 + wlm) * 640;
    float acc[4][4] = {};
    for (int k0 = 0; k0 < 640; k0 += 16) {
        const int k = k0 + alk;
        h16x8 av = {};
        if (rm >= 0) av = (k < 320) ? *(const h16x8*)(arow0 + k)
                                    : *(const h16x8*)(arow1 + (k - 320));
        const float4 wv = *(const float4*)(wrow + k0 + wlk);
        __syncthreads();
        if (tid < 128) {
            #pragma unroll
            for (int j = 0; j < 8; ++j) As[alk + j][alm] = (float)av[j];
        }
        Ws[wlk + 0][wlm] = wv.x; Ws[wlk + 1][wlm] = wv.y;
        Ws[wlk + 2][wlm] = wv.z; Ws[wlk + 3][wlm] = wv.w;
        __syncthreads();
        #pragma unroll
        for (int kk = 0; kk < 16; ++kk) {
            const float4 a4 = *(const float4*)&As[kk][trow << 2];
            const float4 w4 = *(const float4*)&Ws[kk][tcol << 2];
            const float aa[4] = {a4.x, a4.y, a4.z, a4.w};
            const float ww[4] = {w4.x, w4.y, w4.z, w4.w};
            #pragma unroll
            for (int i = 0; i < 4; ++i)
                #pragma unroll
                for (int j = 0; j < 4; ++j)
                    acc[i][j] = fmaf(aa[i], ww[j], acc[i][j]);
        }
    }
    #pragma unroll
    for (int i = 0; i < 4; ++i) {
        const int rr = rows_s[(trow << 2) + i];
        if (rr < 0) continue;
        #pragma unroll
        for (int j = 0; j < 4; ++j) {
            const int cc = cn0 + (tcol << 2) + j;
            comp[(size_t)rr * nWD + cc] = (h16)tanhf(acc[i][j] + redb[l * nWD + cc]);
        }
    }
}

// =================== fused scan v2: 4 uniform roles (tok, ac, sx, st) ===================
// 1024 blocks x 256 thr (4 blocks/CU). role = blk>>8: 0=tok 1=ac 2=sx 3=st.
// Every block: 16 h (64 gate rows) x 8 batches, ONE 64-VGPR weight slice, one dot.
// sx computes X2[t] = (tokh[t]+P1[t])·sWih^T + sb (no self-recurrence), lags tok,
// feeds st via depth-8 stamped ring. st = single sWhh dot + X2 add. XCD-local g.
// K-slices 16B-interleaved ((i*4+kg)*8) -> conflict-free ds reads.
__global__ __launch_bounds__(256, 4)
void fused_scan_k(const h16* __restrict__ tW16, const h16* __restrict__ sWhh16,
                  const h16* __restrict__ sWih16, const h16* __restrict__ aW16,
                  const h16* __restrict__ gxTok, const float* __restrict__ acTab,
                  const int* __restrict__ actb, const h16* __restrict__ P1h,
                  const float* __restrict__ sbias,
                  u64t* __restrict__ hq_tok, u64t* __restrict__ hq_st, u64t* __restrict__ hq_ac,
                  u64t* __restrict__ hq_ts, u64t* __restrict__ hq_x2,
                  h16* __restrict__ tokrec, h16* __restrict__ hsrec, h16* __restrict__ harec)
{
    __shared__ __align__(16) h16 hsmS[8][nH];      // 8 KB
    __shared__ float ps[4][8][65];                 // 8.3 KB
    __shared__ float gexF[64 * 9];                 // 2.3 KB
    __shared__ int aidx[8];
    const int blk = blockIdx.x, tid = threadIdx.x;
    const int role = blk >> 8, sub = blk & 255;
    const int g = sub & 7, jb = sub >> 3;          // XCD-local group g; jb in [0,32)
    const int kg = tid & 3, r = tid >> 2;          // K-slice (interleaved), gate row
    const int grow = (r >> 4) * nH + (jb << 4) + (r & 15);
    const int rr = tid & 63, bq = tid >> 6;        // reduce mapping
    const int growR = (rr >> 4) * nH + (jb << 4) + (rr & 15);
    const size_t gbase = (size_t)g << 11;
    const h16* W = (role == 0) ? tW16 : (role == 1) ? aW16 : (role == 2) ? sWih16 : sWhh16;
    u64t* hq_self = (role == 0) ? hq_tok : (role == 1) ? hq_ac : hq_st;
    h16x8 wreg[16];
    {
        const h16* Wp = W + (size_t)grow * nH;
        #pragma unroll
        for (int i = 0; i < 16; ++i) wreg[i] = *(const h16x8*)(Wp + (((i << 2) + kg) << 3));
        #pragma unroll
        for (int i = 0; i < 16; ++i) PINV(wreg[i]);
    }
    const float sxb = (role == 2) ? sbias[growR] : 0.0f;
    float creg[2] = {0.0f, 0.0f};
    for (int t = 0; t < nS; ++t) {
        float gp[2] = {0.0f, 0.0f};
        if (role == 0) {
            #pragma unroll
            for (int u = 0; u < 2; ++u)
                gp[u] = (float)gxTok[(size_t)((t << 6) + (g << 3) + (bq << 1) + u) * nG + growR];
        } else if (role == 1 && tid < 8) {
            aidx[tid] = actb[((g << 3) + tid) * nAc + t];
        }
        // ---- fill hsmS (2048 u32 words / 256 thr = 8 each) ----
        if (role == 2) {
            const int want = t + 1;                         // tok h[t]
            u64t* base = hq_ts + (size_t)(t & 3) * 16384 + gbase;
            const unsigned* p1p = (const unsigned*)(P1h + (size_t)t * BH) + (g << 11);
            u64t v[8];
            #pragma unroll
            for (int i = 0; i < 8; ++i)
                v[i] = __hip_atomic_load(base + tid + (i << 8), __ATOMIC_RELAXED, __HIP_MEMORY_SCOPE_AGENT);
            #pragma unroll
            for (int i = 0; i < 8; ++i) {
                while ((int)(v[i] >> 32) != want) {
                    __builtin_amdgcn_s_sleep(1);
                    v[i] = __hip_atomic_load(base + tid + (i << 8), __ATOMIC_RELAXED, __HIP_MEMORY_SCOPE_AGENT);
                }
                const h16x2 tv = __builtin_bit_cast(h16x2, (unsigned)v[i]);
                const h16x2 pv = __builtin_bit_cast(h16x2, p1p[tid + (i << 8)]);
                h16x2 sum; sum[0] = tv[0] + pv[0]; sum[1] = tv[1] + pv[1];
                ((unsigned*)hsmS)[tid + (i << 8)] = __builtin_bit_cast(unsigned, sum);
            }
        } else if (t == 0) {
            #pragma unroll
            for (int i = 0; i < 8; ++i) ((unsigned*)hsmS)[tid + (i << 8)] = 0u;
        } else {
            const int want = t;
            u64t* base = hq_self + (size_t)((t - 1) & 1) * 16384 + gbase;
            u64t v[8];
            #pragma unroll
            for (int i = 0; i < 8; ++i)
                v[i] = __hip_atomic_load(base + tid + (i << 8), __ATOMIC_RELAXED, __HIP_MEMORY_SCOPE_AGENT);
            #pragma unroll
            for (int i = 0; i < 8; ++i) {
                while ((int)(v[i] >> 32) != want) {
                    __builtin_amdgcn_s_sleep(1);
                    v[i] = __hip_atomic_load(base + tid + (i << 8), __ATOMIC_RELAXED, __HIP_MEMORY_SCOPE_AGENT);
                }
                ((unsigned*)hsmS)[tid + (i << 8)] = (unsigned)v[i];
            }
        }
        __syncthreads();
        if (role == 1) {
            #pragma unroll
            for (int u = 0; u < 2; ++u)
                gp[u] = acTab[(size_t)aidx[(bq << 1) + u] * nG + growR];
        }
        // ---- dot: 16 i x 8 b, slice-interleaved reads ----
        __builtin_amdgcn_s_setprio(1);
        float acc[8] = {0,0,0,0,0,0,0,0};
        #pragma unroll
        for (int i = 0; i < 16; ++i) {
            const h16x2* wp = (const h16x2*)&wreg[i];
            const int ko = ((i << 2) + kg) << 3;
            #pragma unroll
            for (int b = 0; b < 8; ++b) {
                h16x8 hv = *(const h16x8*)(&hsmS[b][ko]);
                const h16x2* hp = (const h16x2*)&hv;
                acc[b] = FDOT2(hp[0], wp[0], acc[b]);
                acc[b] = FDOT2(hp[1], wp[1], acc[b]);
                acc[b] = FDOT2(hp[2], wp[2], acc[b]);
                acc[b] = FDOT2(hp[3], wp[3], acc[b]);
            }
        }
        __builtin_amdgcn_s_setprio(0);
        #pragma unroll
        for (int b = 0; b < 8; ++b) ps[kg][b][r] = acc[b];
        __syncthreads();
        // ---- reduce: thread (rr, b = 2bq+u) ----
        #pragma unroll
        for (int u = 0; u < 2; ++u) {
            const int b = (bq << 1) + u;
            float s = (role == 2) ? sxb : gp[u];
            #pragma unroll
            for (int k2 = 0; k2 < 4; ++k2) s += ps[k2][b][rr];
            if (role == 3) {
                // add X2[t] (stamped, from sx)
                const int want = t + 1;
                u64t* xp = hq_x2 + (size_t)(t & 7) * 65536 + ((size_t)g << 13) + (b << 10) + (jb << 5) + (rr >> 1);
                u64t v = __hip_atomic_load(xp, __ATOMIC_RELAXED, __HIP_MEMORY_SCOPE_AGENT);
                while ((int)(v >> 32) != want) {
                    __builtin_amdgcn_s_sleep(1);
                    v = __hip_atomic_load(xp, __ATOMIC_RELAXED, __HIP_MEMORY_SCOPE_AGENT);
                }
                const h16x2 xv = __builtin_bit_cast(h16x2, (unsigned)v);
                s += (float)xv[rr & 1];
            }
            gexF[rr * 9 + b] = s;
        }
        // ---- flow control ----
        if (role == 0 && t >= 4 && tid == 0) {
            // before writing hq_ts slot t&3 (holds h[t-4]): sx must have consumed it
            u64t* fp = hq_x2 + (size_t)((t - 4) & 7) * 65536 + ((size_t)g << 13);
            u64t v = __hip_atomic_load(fp, __ATOMIC_RELAXED, __HIP_MEMORY_SCOPE_AGENT);
            while ((int)(v >> 32) < t - 3) {
                __builtin_amdgcn_s_sleep(1);
                v = __hip_atomic_load(fp, __ATOMIC_RELAXED, __HIP_MEMORY_SCOPE_AGENT);
            }
        }
        if (role == 2 && t >= 8 && tid == 0) {
            // before writing hq_x2 slot t&7 (holds X2[t-8]): st must have consumed it
            u64t* fp = hq_st + (size_t)(t & 1) * 16384 + gbase;
            u64t v = __hip_atomic_load(fp, __ATOMIC_RELAXED, __HIP_MEMORY_SCOPE_AGENT);
            while ((int)(v >> 32) < t - 7) {
                __builtin_amdgcn_s_sleep(1);
                v = __hip_atomic_load(fp, __ATOMIC_RELAXED, __HIP_MEMORY_SCOPE_AGENT);
            }
        }
        __syncthreads();
        // ---- output ----
        if (role == 2) {
            const int rp = tid >> 3, b2 = tid & 7;    // rp in [0,32): row-pair
            const float v0 = gexF[(rp << 1) * 9 + b2];
            const float v1 = gexF[((rp << 1) + 1) * 9 + b2];
            h16x2 p; p[0] = (h16)v0; p[1] = (h16)v1;
            const u64t word = ((u64t)(unsigned)(t + 1) << 32) | __builtin_bit_cast(unsigned, p);
            __hip_atomic_store(hq_x2 + (size_t)(t & 7) * 65536 + ((size_t)g << 13) + (b2 << 10) + (jb << 5) + rp,
                               word, __ATOMIC_RELAXED, __HIP_MEMORY_SCOPE_AGENT);
        } else if (tid < 64) {
            const int qp = tid >> 3, b2 = tid & 7;    // qp in [0,8): h-pair
            const int j0 = qp << 1;
            float hn[2];
            #pragma unroll
            for (int u = 0; u < 2; ++u) {
                const int j = j0 + u;
                const float gi = gexF[j * 9 + b2], gf = gexF[(16 + j) * 9 + b2];
                const float gg = gexF[(32 + j) * 9 + b2], go = gexF[(48 + j) * 9 + b2];
                const float cn = sigf(gf) * creg[u] + sigf(gi) * tanhf(gg);
                hn[u] = sigf(go) * tanhf(cn);
                creg[u] = cn;
            }
            const int bg = (g << 3) + b2;
            h16x2 hp2; hp2[0] = (h16)hn[0]; hp2[1] = (h16)hn[1];
            const u64t word = ((u64t)(unsigned)(t + 1) << 32) | __builtin_bit_cast(unsigned, hp2);
            const size_t woff = ((size_t)b2 << 8) + (jb << 3) + qp;
            __hip_atomic_store(hq_self + (size_t)(t & 1) * 16384 + gbase + woff,
                               word, __ATOMIC_RELAXED, __HIP_MEMORY_SCOPE_AGENT);
            if (role == 0)
                __hip_atomic_store(hq_ts + (size_t)(t & 3) * 16384 + gbase + woff,
                                   word, __ATOMIC_RELAXED, __HIP_MEMORY_SCOPE_AGENT);
            h16* rec = (role == 0) ? (tokrec + (size_t)t * BH)
                     : (role == 1) ? (harec + (size_t)t * BH)
                                   : (hsrec + (size_t)(t + 2) * BH);
            *(h16x2*)(rec + (size_t)bg * nH + (jb << 4) + j0) = hp2;
        }
    }
}

// ---------------- per-(t,b) logits + log-softmax loss ----------------
__global__ __launch_bounds__(128)
void loss_k(const h16* __restrict__ hidden, const float* __restrict__ f2aW,
            const float* __restrict__ f2ab, const int* __restrict__ actb,
            float* __restrict__ losses)
{
    const int r = blockIdx.x;
    const int t = r >> 6, b = r & 63;
    __shared__ __align__(16) float hrow[nH];
    __shared__ float lg[nNA + 1];
    const int tid = threadIdx.x;
    if (tid < 64) {
        const h16x8 v = ((const h16x8*)(hidden + (size_t)r * nH))[tid];
        #pragma unroll
        for (int j = 0; j < 8; ++j) hrow[tid * 8 + j] = (float)v[j];
    }
    __syncthreads();
    if (tid < nNA) {
        const float* wr = f2aW + (size_t)tid * nH;
        float a = f2ab[tid];
        for (int k = 0; k < nH; k += 4) {
            const float4 wv = *(const float4*)(wr + k);
            const float4 hv = *(const float4*)(&hrow[k]);
            a = fmaf(wv.x, hv.x, a); a = fmaf(wv.y, hv.y, a);
            a = fmaf(wv.z, hv.z, a); a = fmaf(wv.w, hv.w, a);
        }
        lg[tid] = a;
    }
    __syncthreads();
    if (tid < 64) {
        float m = -1e30f;
        for (int i = tid; i < nNA; i += 64) m = fmaxf(m, lg[i]);
        #pragma unroll
        for (int o = 32; o > 0; o >>= 1) m = fmaxf(m, __shfl_xor(m, o));
        float s = 0.0f;
        for (int i = tid; i < nNA; i += 64) s += __expf(lg[i] - m);
        #pragma unroll
        for (int o = 32; o > 0; o >>= 1) s += __shfl_xor(s, o);
        if (tid == 0) {
            const int a = actb[b * nAc + t];
            losses[r] = m + logf(s) - lg[a];
        }
    }
}

__global__ __launch_bounds__(256)
void reduce_k(const float* __restrict__ losses, float* __restrict__ out)
{
    __shared__ float sm[256];
    const int tid = threadIdx.x;
    float a = 0.0f;
    for (int i = tid; i < nS * nB; i += 256) a += losses[i];
    sm[tid] = a; __syncthreads();
    for (int s = 128; s > 0; s >>= 1) { if (tid < s) sm[tid] += sm[tid + s]; __syncthreads(); }
    if (tid == 0) out[0] = sm[0] * (1.0f / 16384.0f);
}

// ---------------- launch ----------------
extern "C" void kernel_launch(void* const* d_in, const int* in_sizes, int n_in,
                              void* d_out, int out_size, void* d_ws, size_t ws_size,
                              hipStream_t stream)
{
    const int*   tokb  = (const int*)  d_in[0];
    const int*   posb  = (const int*)  d_in[1];
    const int*   actb  = (const int*)  d_in[3];
    const float* wemb  = (const float*)d_in[4];
    const float* pemb  = (const float*)d_in[5];
    const float* aemb  = (const float*)d_in[6];
    const float* tWih  = (const float*)d_in[7];
    const float* tWhh  = (const float*)d_in[8];
    const float* tb    = (const float*)d_in[9];
    const float* sWih  = (const float*)d_in[10];
    const float* sWhh  = (const float*)d_in[11];
    const float* sb    = (const float*)d_in[12];
    const float* aWih  = (const float*)d_in[13];
    const float* aWhh  = (const float*)d_in[14];
    const float* ab    = (const float*)d_in[15];
    const float* redW  = (const float*)d_in[16];
    const float* redb  = (const float*)d_in[17];
    const float* compW = (const float*)d_in[18];
    const float* compb = (const float*)d_in[19];
    const float* h2fW  = (const float*)d_in[20];
    const float* h2fb  = (const float*)d_in[21];
    const float* f2aW  = (const float*)d_in[22];
    const float* f2ab  = (const float*)d_in[23];

    // ---- workspace carve ----
    char* base = (char*)d_ws;
    auto carve = [&](size_t bytes) { char* p = base; base += (bytes + 255) & ~(size_t)255; return p; };
    h16*   tok    = (h16*)  carve((size_t)nB * nS * nWD * 2);
    h16*   Xh     = (h16*)  carve((size_t)nS * nB * nG * 2);
    h16*   comph  = (h16*)  carve((size_t)nS * nB * nWD * 2);
    h16*   P1h    = (h16*)  carve((size_t)nS * BH * 2);
    h16*   tokrec = (h16*)  carve((size_t)nS * BH * 2);
    h16*   hsrec  = (h16*)  carve((size_t)(nS + 2) * BH * 2);
    h16*   harec  = (h16*)  carve((size_t)nS * BH * 2);
    h16*   tW16   = (h16*)  carve((size_t)nG * nH * 2);
    h16*   sW16   = (h16*)  carve((size_t)nG * nH * 2);
    h16*   aW16   = (h16*)  carve((size_t)nG * nH * 2);
    h16*   tWih16 = (h16*)  carve((size_t)nG * nWD * 2);
    h16*   sWih16 = (h16*)  carve((size_t)nG * nH * 2);
    h16*   h2f16  = (h16*)  carve((size_t)nH * nFH * 2);
    h16*   comp16 = (h16*)  carve((size_t)nH * nWD * 2);
    float* acTab  = (float*)carve((size_t)nNA * nG * 4);
    u64t*  hbuf   = (u64t*) carve((size_t)2 * 16384 * 8);
    u64t*  spbuf  = (u64t*) carve((size_t)2 * 16384 * 8);
    u64t*  apbuf  = (u64t*) carve((size_t)2 * 16384 * 8);
    u64t*  tsbuf  = (u64t*) carve((size_t)4 * 16384 * 8);
    u64t*  x2buf  = (u64t*) carve((size_t)8 * 65536 * 8);          // sx->st X2 ring (4 MB)
    float* losses = (float*)carve((size_t)nS * nB * 4);
    int*   lab      = (int*)carve((size_t)nS * nB * 4);
    int*   counts   = (int*)carve(nLB * 4);
    int*   offs     = (int*)carve((nLB + 1) * 4);
    int*   fill     = (int*)carve(nLB * 4);
    int*   tl_lab   = (int*)carve(320 * 4);
    int*   tl_start = (int*)carve(320 * 4);
    int*   tl_cnt   = (int*)carve(320 * 4);
    int*   ntiles   = (int*)carve(4);
    int*   idxb     = (int*)carve((size_t)nS * nB * 4);

    init_k<<<dim3(256), dim3(256), 0, stream>>>(hsrec, counts, fill, hbuf, spbuf, apbuf, tsbuf, x2buf);
    embed_k<<<dim3(nB * nS), dim3(64), 0, stream>>>(tokb, posb, wemb, pemb, tok);
    actab_k<<<dim3(nNA), dim3(256), 0, stream>>>(aemb, aWih, ab, acTab);
    cvt_k<<<dim3(1024), dim3(256), 0, stream>>>(tWhh, tW16, 262144);
    cvt_k<<<dim3(1024), dim3(256), 0, stream>>>(sWhh, sW16, 262144);
    cvt_k<<<dim3(1024), dim3(256), 0, stream>>>(aWhh, aW16, 262144);
    cvt_k<<<dim3(640),  dim3(256), 0, stream>>>(tWih, tWih16, 163840);
    cvt_k<<<dim3(1024), dim3(256), 0, stream>>>(sWih, sWih16, 262144);
    cvt_k<<<dim3(1280), dim3(256), 0, stream>>>(h2fW, h2f16, 327680);
    cvt_k<<<dim3(160),  dim3(256), 0, stream>>>(compW, comp16, 40960);
    // tokX = tok @ tok_Wih.T + tok_b -> Xh (MFMA)
    mgemm_k<0,false><<<dim3(256, 32), dim3(256), 0, stream>>>(tWih16, tb, tok, nullptr, nullptr, Xh, nWD, nG);
    hist_k<<<dim3(64), dim3(256), 0, stream>>>(actb, lab, counts);
    tiles_k<<<dim3(1), dim3(64), 0, stream>>>(counts, offs, tl_lab, tl_start, tl_cnt, ntiles);
    scatter_k<<<dim3(64), dim3(256), 0, stream>>>(lab, offs, fill, idxb);
    comp_gemm_k<<<dim3(304, 5), dim3(256), 0, stream>>>(tok, redW, redb, idxb, tl_lab, tl_start, tl_cnt, ntiles, comph);
    // P1 = composed @ comp_W.T + comp_b (MFMA, MODE 5)
    mgemm_k<5,false><<<dim3(256, 8), dim3(256), 0, stream>>>(comp16, compb, comph, nullptr, nullptr, P1h, nWD, nH);
    // fused scan v2: tok + ac + sx + st (1024 blocks x 256 thr)
    {
        const h16* a0 = tW16; const h16* a1 = sW16; const h16* a2 = sWih16; const h16* a3 = aW16;
        const h16* a4 = Xh; const float* a5 = acTab; const int* a6 = actb;
        const h16* a7 = P1h; const float* a8 = sb;
        u64t* a9 = hbuf; u64t* a10 = spbuf; u64t* a11 = apbuf; u64t* a12 = tsbuf; u64t* a13 = x2buf;
        h16* a14 = tokrec; h16* a15 = hsrec; h16* a16 = harec;
        void* args[] = {&a0, &a1, &a2, &a3, &a4, &a5, &a6, &a7, &a8, &a9, &a10, &a11, &a12, &a13, &a14, &a15, &a16};
        hipLaunchCooperativeKernel((const void*)fused_scan_k, dim3(1024), dim3(256), args, 0, stream);
    }
    // hidden = relu(feat @ h2f_W.T + h2f_b) -> Xh (MFMA)
    mgemm_k<3,true><<<dim3(256, 8), dim3(256), 0, stream>>>(h2f16, h2fb, hsrec, tokrec, harec, Xh, nFH, nH);
    loss_k<<<dim3(nS * nB), dim3(128), 0, stream>>>(Xh, f2aW, f2ab, actb, losses);
    reduce_k<<<dim3(1), dim3(256), 0, stream>>>(losses, (float*)d_out);
}

// Round 13
// 3038.442 us; speedup vs baseline: 1.2757x; 1.2757x over previous
//
#include <hip/hip_runtime.h>
#include <math.h>

constexpr int nB = 64, nS = 256, nAc = 256, nH = 512, nG = 2048;
constexpr int nWD = 320, nNA = 75, nLB = 48, nFH = 2560;
constexpr int BH = nB * nH; // 32768

typedef _Float16 h16;
typedef _Float16 h16x8 __attribute__((ext_vector_type(8)));
typedef _Float16 h16x4 __attribute__((ext_vector_type(4)));
typedef _Float16 h16x2 __attribute__((ext_vector_type(2)));
typedef float f32x4 __attribute__((ext_vector_type(4)));
typedef unsigned long long u64t;

__device__ __forceinline__ float sigf(float x) { return 1.0f / (1.0f + __expf(-x)); }

#if __has_builtin(__builtin_amdgcn_fdot2)
#define FDOT2(a, b, c) __builtin_amdgcn_fdot2((a), (b), (c), false)
#else
__device__ __forceinline__ float FDOT2(h16x2 a, h16x2 b, float c) {
    return c + (float)a[0] * (float)b[0] + (float)a[1] * (float)b[1];
}
#endif

#define PINV(x) asm volatile("" : "+v"(x))

// ---------------- init: zero hsrec prefix + transport buffers + counters ----------------
__global__ void init_k(h16* __restrict__ hsrec, int* __restrict__ counts, int* __restrict__ fill,
                       u64t* __restrict__ hbuf, u64t* __restrict__ spbuf, u64t* __restrict__ apbuf,
                       u64t* __restrict__ tsbuf)
{
    int i = blockIdx.x * 256 + threadIdx.x;   // grid 256x256 = 65536
    if (i < 2 * BH) hsrec[i] = (h16)0.0f;
    if (i < 32768) { hbuf[i] = 0; spbuf[i] = 0; apbuf[i] = 0; }
    tsbuf[i] = 0;                             // 4 x 16384 ring
    if (i < nLB) { counts[i] = 0; fill[i] = 0; }
}

// ---------------- generic fp32 -> fp16 conversion ----------------
__global__ __launch_bounds__(256)
void cvt_k(const float* __restrict__ src, h16* __restrict__ dst, int n4)
{
    const int i = blockIdx.x * 256 + threadIdx.x;
    if (i < n4) {
        const float4 a = ((const float4*)src)[i];
        h16x4 v; v[0]=(h16)a.x; v[1]=(h16)a.y; v[2]=(h16)a.z; v[3]=(h16)a.w;
        ((h16x4*)dst)[i] = v;
    }
}

// ---------------- embedding gather -> tok fp16 [b][s][0:320] ----------------
__global__ __launch_bounds__(64)
void embed_k(const int* __restrict__ tokb, const int* __restrict__ posb,
             const float* __restrict__ wemb, const float* __restrict__ pemb,
             h16* __restrict__ tok)
{
    const int r = blockIdx.x;            // b*nS + s
    const int tid = threadIdx.x;
    const int tk = tokb[r], pp = posb[r];
    h16x8* d = (h16x8*)(tok + (size_t)r * nWD);
    if (tid < 32) {
        const float4* sw = (const float4*)(wemb + (size_t)tk * 256);
        const float4 a = sw[2 * tid], b = sw[2 * tid + 1];
        h16x8 o;
        o[0]=(h16)a.x; o[1]=(h16)a.y; o[2]=(h16)a.z; o[3]=(h16)a.w;
        o[4]=(h16)b.x; o[5]=(h16)b.y; o[6]=(h16)b.z; o[7]=(h16)b.w;
        d[tid] = o;
    } else if (tid < 40) {
        const int q = tid - 32;
        const float4* sp = (const float4*)(pemb + (size_t)pp * 64);
        const float4 a = sp[2 * q], b = sp[2 * q + 1];
        h16x8 o;
        o[0]=(h16)a.x; o[1]=(h16)a.y; o[2]=(h16)a.z; o[3]=(h16)a.w;
        o[4]=(h16)b.x; o[5]=(h16)b.y; o[6]=(h16)b.z; o[7]=(h16)b.w;
        d[32 + q] = o;
    }
}

// ---------------- action-gate table: acTab[a][j] = aemb[a]·aWih[j] + ab[j] ----------------
__global__ __launch_bounds__(256)
void actab_k(const float* __restrict__ aemb, const float* __restrict__ aWih,
             const float* __restrict__ ab, float* __restrict__ acTab)
{
    const int a = blockIdx.x;            // 0..74
    __shared__ float ae[64];
    const int tid = threadIdx.x;
    if (tid < 64) ae[tid] = aemb[a * 64 + tid];
    __syncthreads();
    for (int j = tid; j < nG; j += 256) {
        const float* wr = aWih + (size_t)j * 64;
        float s = ab[j];
        #pragma unroll
        for (int k = 0; k < 64; k += 4) {
            const float4 w = *(const float4*)(wr + k);
            s = fmaf(w.x, ae[k], s);     s = fmaf(w.y, ae[k + 1], s);
            s = fmaf(w.z, ae[k + 2], s); s = fmaf(w.w, ae[k + 3], s);
        }
        acTab[(size_t)a * nG + j] = s;
    }
}

// =============== MFMA fp16 GEMM: C[r][n] = Arow(r)·Wm[n][:] + bias[n] ===============
template<int MODE, bool RELU>
__global__ __launch_bounds__(256)
void mgemm_k(const h16* __restrict__ Wm, const float* __restrict__ bias,
             const h16* __restrict__ A0, const h16* __restrict__ A1,
             const h16* __restrict__ A2, h16* __restrict__ C, int Ktot, int ldC)
{
    const int bm = blockIdx.x << 6, bn = blockIdx.y << 6;
    const int tid = threadIdx.x;
    const int lane = tid & 63, wave = tid >> 6;
    const int wr = wave >> 1, wc = wave & 1;
    __shared__ __align__(16) h16 As[64][40];
    __shared__ __align__(16) h16 Ws[64][40];
    const int srow = tid >> 2, sk = (tid & 3) << 3;
    const int r3 = bm + srow;
    const h16* arow = nullptr;
    if (MODE == 0) { const int b = r3 & 63, s = r3 >> 6; arow = A0 + ((size_t)b * nS + s) * nWD; }
    if (MODE == 5) { arow = A0 + (size_t)r3 * nWD; }
    const h16* wrow = Wm + (size_t)(bn + srow) * Ktot;
    f32x4 acc[2][2] = {};
    for (int k0 = 0; k0 < Ktot; k0 += 32) {
        h16x8 av, wv;
        if (MODE == 3) {
            const int k = k0 + sk;
            const int p = k >> 9;
            const h16* base = (p == 0) ? A0 + 2 * BH : (p == 1) ? A0 + BH
                            : (p == 2) ? A0 : (p == 3) ? A1 : A2;
            av = *(const h16x8*)(base + (size_t)r3 * nH + (k & 511));
        } else {
            av = *(const h16x8*)(arow + k0 + sk);
        }
        wv = *(const h16x8*)(wrow + k0 + sk);
        __syncthreads();
        *(h16x8*)(&As[srow][sk]) = av;
        *(h16x8*)(&Ws[srow][sk]) = wv;
        __syncthreads();
        const int fk = (lane >> 4) << 3;
        const int fr = lane & 15;
        h16x8 af0 = *(const h16x8*)(&As[(wr << 5) + fr][fk]);
        h16x8 af1 = *(const h16x8*)(&As[(wr << 5) + 16 + fr][fk]);
        h16x8 bf0 = *(const h16x8*)(&Ws[(wc << 5) + fr][fk]);
        h16x8 bf1 = *(const h16x8*)(&Ws[(wc << 5) + 16 + fr][fk]);
        acc[0][0] = __builtin_amdgcn_mfma_f32_16x16x32_f16(af0, bf0, acc[0][0], 0, 0, 0);
        acc[0][1] = __builtin_amdgcn_mfma_f32_16x16x32_f16(af0, bf1, acc[0][1], 0, 0, 0);
        acc[1][0] = __builtin_amdgcn_mfma_f32_16x16x32_f16(af1, bf0, acc[1][0], 0, 0, 0);
        acc[1][1] = __builtin_amdgcn_mfma_f32_16x16x32_f16(af1, bf1, acc[1][1], 0, 0, 0);
    }
    #pragma unroll
    for (int mi = 0; mi < 2; ++mi) {
        #pragma unroll
        for (int ni = 0; ni < 2; ++ni) {
            const int col = bn + (wc << 5) + (ni << 4) + (lane & 15);
            const float bs = bias[col];
            #pragma unroll
            for (int rg = 0; rg < 4; ++rg) {
                const int row = bm + (wr << 5) + (mi << 4) + ((lane >> 4) << 2) + rg;
                float x = acc[mi][ni][rg] + bs;
                if (RELU) x = fmaxf(x, 0.0f);
                C[(size_t)row * ldC + col] = (h16)x;
            }
        }
    }
}

// ---------------- label sort for red_W batched GEMM ----------------
__global__ void hist_k(const int* __restrict__ actb, int* __restrict__ lab, int* __restrict__ counts)
{
    const int r = blockIdx.x * 256 + threadIdx.x;
    const int t = r >> 6, b = r & 63;
    const int a = actb[b * nAc + t];
    const int l = a % nLB;
    lab[r] = l;
    atomicAdd(&counts[l], 1);
}

__global__ void tiles_k(const int* __restrict__ counts, int* __restrict__ offs,
                        int* __restrict__ tl_lab, int* __restrict__ tl_start,
                        int* __restrict__ tl_cnt, int* __restrict__ ntiles)
{
    if (blockIdx.x == 0 && threadIdx.x == 0) {
        int o = 0, nt = 0;
        for (int l = 0; l < nLB; ++l) {
            offs[l] = o;
            const int c = counts[l];
            for (int s0 = 0; s0 < c; s0 += 64) {
                tl_lab[nt] = l; tl_start[nt] = o + s0; tl_cnt[nt] = min(64, c - s0); ++nt;
            }
            o += c;
        }
        offs[nLB] = o;
        ntiles[0] = nt;
    }
}

__global__ void scatter_k(const int* __restrict__ lab, const int* __restrict__ offs,
                          int* __restrict__ fill, int* __restrict__ idx)
{
    const int r = blockIdx.x * 256 + threadIdx.x;
    const int l = lab[r];
    const int pos = offs[l] + atomicAdd(&fill[l], 1);
    idx[pos] = r;
}

// composed[r][i] = tanh( pair(r)·red_W[l][i][:] + red_b[l][i] ), rows grouped by label
__global__ __launch_bounds__(256)
void comp_gemm_k(const h16* __restrict__ tok, const float* __restrict__ redW,
                 const float* __restrict__ redb, const int* __restrict__ idx,
                 const int* __restrict__ tl_lab, const int* __restrict__ tl_start,
                 const int* __restrict__ tl_cnt, const int* __restrict__ ntiles,
                 h16* __restrict__ comp)
{
    const int tile = blockIdx.x;
    if (tile >= ntiles[0]) return;
    const int cn0 = blockIdx.y << 6;
    const int l = tl_lab[tile], rst = tl_start[tile], mrows = tl_cnt[tile];
    __shared__ int rows_s[64];
    __shared__ __align__(16) float As[16][68];
    __shared__ __align__(16) float Ws[16][68];
    const int tid = threadIdx.x;
    if (tid < 64) rows_s[tid] = (tid < mrows) ? idx[rst + tid] : -1;
    __syncthreads();
    const int alm = tid >> 1, alk = (tid & 1) << 3;
    const int wlm = tid >> 2, wlk = (tid & 3) << 2;
    const int trow = tid >> 4, tcol = tid & 15;
    const int rm = (tid < 128) ? rows_s[alm] : -1;
    const h16* arow0 = tok;
    const h16* arow1 = tok;
    if (rm >= 0) {
        const int b = rm & 63, t = rm >> 6;
        arow0 = tok + ((size_t)b * nS + t) * nWD;
        arow1 = tok + ((size_t)b * nS + max(t - 1, 0)) * nWD;
    }
    const float* wrow = redW + (size_t)l * (320 * 640) + (size_t)(cn0 + wlm) * 640;
    float acc[4][4] = {};
    for (int k0 = 0; k0 < 640; k0 += 16) {
        const int k = k0 + alk;
        h16x8 av = {};
        if (rm >= 0) av = (k < 320) ? *(const h16x8*)(arow0 + k)
                                    : *(const h16x8*)(arow1 + (k - 320));
        const float4 wv = *(const float4*)(wrow + k0 + wlk);
        __syncthreads();
        if (tid < 128) {
            #pragma unroll
            for (int j = 0; j < 8; ++j) As[alk + j][alm] = (float)av[j];
        }
        Ws[wlk + 0][wlm] = wv.x; Ws[wlk + 1][wlm] = wv.y;
        Ws[wlk + 2][wlm] = wv.z; Ws[wlk + 3][wlm] = wv.w;
        __syncthreads();
        #pragma unroll
        for (int kk = 0; kk < 16; ++kk) {
            const float4 a4 = *(const float4*)&As[kk][trow << 2];
            const float4 w4 = *(const float4*)&Ws[kk][tcol << 2];
            const float aa[4] = {a4.x, a4.y, a4.z, a4.w};
            const float ww[4] = {w4.x, w4.y, w4.z, w4.w};
            #pragma unroll
            for (int i = 0; i < 4; ++i)
                #pragma unroll
                for (int j = 0; j < 4; ++j)
                    acc[i][j] = fmaf(aa[i], ww[j], acc[i][j]);
        }
    }
    #pragma unroll
    for (int i = 0; i < 4; ++i) {
        const int rr = rows_s[(trow << 2) + i];
        if (rr < 0) continue;
        #pragma unroll
        for (int j = 0; j < 4; ++j) {
            const int cc = cn0 + (tcol << 2) + j;
            comp[(size_t)rr * nWD + cc] = (h16)tanhf(acc[i][j] + redb[l * nWD + cc]);
        }
    }
}

// =================== fused pipelined scan: tok + ac + st chains ===================
// Round-13: revert to round-11 structure (best fused: 2.486 ms) — XCD-local groups,
// depth-4 tok->st ring, 2-rows/thread dot — with busy-poll on the data waits
// (s_sleep removed from hot stamp polls; steady-state polls succeed ~first try,
// sleep only added quantization on the handoff edge). Flow-control keeps backoff.
__global__ __launch_bounds__(512, 4)
void fused_scan_k(const h16* __restrict__ tW16, const h16* __restrict__ sWhh16,
                  const h16* __restrict__ sWih16, const h16* __restrict__ aW16,
                  const h16* __restrict__ gxTok, const float* __restrict__ acTab,
                  const int* __restrict__ actb, const h16* __restrict__ P1h,
                  const float* __restrict__ sbias,
                  u64t* __restrict__ hq_tok, u64t* __restrict__ hq_st, u64t* __restrict__ hq_ac,
                  u64t* __restrict__ hq_ts,
                  h16* __restrict__ tokrec, h16* __restrict__ hsrec, h16* __restrict__ harec)
{
    __shared__ __align__(16) h16 hsmS[8][nH];     // 8 KB
    __shared__ __align__(16) h16 hsmT[8][nH];     // 8 KB (st only)
    __shared__ float psF[8192];                   // 32 KB
    __shared__ float gexF[1152];                  // 4.5 KB
    __shared__ int aidx[8];
    const int blk = blockIdx.x;
    const int tid = threadIdx.x;

    if (blk < 256) {
        // ---------------- tok (role 0) / ac (role 1) ----------------
        const int role = blk >> 7;
        const int sub = blk & 127;
        const int g = sub & 7, jb = sub >> 3;   // XCD-local: group g on XCD g
        const int kg = tid >> 6;             // [0,8) k-slice of 64, WAVE-UNIFORM
        const int rp = tid & 63;             // row-pair: rows 2rp,2rp+1 in [0,128)
        const int r0 = rp << 1;
        const int grow0 = (r0 >> 5) * nH + (jb << 5) + (r0 & 31);
        // reduce-phase mapping
        const int rr = tid & 127;
        const int bq = tid >> 7;             // [0,4)
        const int growR = (rr >> 5) * nH + (jb << 5) + (rr & 31);
        const h16* W = role ? aW16 : tW16;
        u64t* hq = role ? hq_ac : hq_tok;
        h16x8 w0[8], w1[8];
        {
            const h16* wp0 = W + (size_t)grow0 * nH + (kg << 6);
            const h16* wp1 = wp0 + nH;
            #pragma unroll
            for (int i = 0; i < 8; ++i) {
                w0[i] = *(const h16x8*)(wp0 + (i << 3));
                w1[i] = *(const h16x8*)(wp1 + (i << 3));
            }
            #pragma unroll
            for (int i = 0; i < 8; ++i) { PINV(w0[i]); PINV(w1[i]); }
        }
        float creg[2] = {0.0f, 0.0f};
        const size_t gbase = (size_t)g << 11;          // g*2048 words
        for (int t = 0; t < nS; ++t) {
            float gp[2];
            if (role == 0) {
                #pragma unroll
                for (int u = 0; u < 2; ++u)
                    gp[u] = (float)gxTok[(size_t)((t << 6) + (g << 3) + (bq << 1) + u) * nG + growR];
            } else if (tid < 8) {
                aidx[tid] = actb[((g << 3) + tid) * nAc + t];
            }
            // fill hsmS (busy-poll)
            if (t == 0) {
                ((uint4*)hsmS)[tid] = make_uint4(0u, 0u, 0u, 0u);
            } else {
                const int want = t;
                u64t* base = hq + (size_t)((t - 1) & 1) * 16384 + gbase;
                u64t v[4];
                #pragma unroll
                for (int i = 0; i < 4; ++i)
                    v[i] = __hip_atomic_load(base + tid + (i << 9), __ATOMIC_RELAXED, __HIP_MEMORY_SCOPE_AGENT);
                #pragma unroll
                for (int i = 0; i < 4; ++i) {
                    while ((int)(v[i] >> 32) != want)
                        v[i] = __hip_atomic_load(base + tid + (i << 9), __ATOMIC_RELAXED, __HIP_MEMORY_SCOPE_AGENT);
                    ((unsigned*)hsmS)[tid + (i << 9)] = (unsigned)v[i];
                }
            }
            __syncthreads();
            if (role == 1) {
                #pragma unroll
                for (int u = 0; u < 2; ++u)
                    gp[u] = acTab[(size_t)aidx[(bq << 1) + u] * nG + growR];
            }
            // partial sums: each hsm read (wave-uniform broadcast) feeds 2 rows
            __builtin_amdgcn_s_setprio(1);
            float acc0[8] = {0,0,0,0,0,0,0,0}, acc1[8] = {0,0,0,0,0,0,0,0};
            #pragma unroll
            for (int i = 0; i < 8; ++i) {
                const h16x2* wa = (const h16x2*)&w0[i];
                const h16x2* wb = (const h16x2*)&w1[i];
                #pragma unroll
                for (int b = 0; b < 8; ++b) {
                    h16x8 hv = *(const h16x8*)(&hsmS[b][(kg << 6) + (i << 3)]);
                    const h16x2* hp = (const h16x2*)&hv;
                    acc0[b] = FDOT2(hp[0], wa[0], acc0[b]);
                    acc0[b] = FDOT2(hp[1], wa[1], acc0[b]);
                    acc0[b] = FDOT2(hp[2], wa[2], acc0[b]);
                    acc0[b] = FDOT2(hp[3], wa[3], acc0[b]);
                    acc1[b] = FDOT2(hp[0], wb[0], acc1[b]);
                    acc1[b] = FDOT2(hp[1], wb[1], acc1[b]);
                    acc1[b] = FDOT2(hp[2], wb[2], acc1[b]);
                    acc1[b] = FDOT2(hp[3], wb[3], acc1[b]);
                }
            }
            __builtin_amdgcn_s_setprio(0);
            #pragma unroll
            for (int b = 0; b < 8; ++b) {
                float2 pv; pv.x = acc0[b]; pv.y = acc1[b];
                *(float2*)&psF[(((kg << 3) + b) << 7) + r0] = pv;
            }
            __syncthreads();
            // reduce: thread handles (rr, b = 2*bq+u)
            #pragma unroll
            for (int u = 0; u < 2; ++u) {
                const int b = (bq << 1) + u;
                float s = gp[u];
                #pragma unroll
                for (int k2 = 0; k2 < 8; ++k2) s += psF[(((k2 << 3) + b) << 7) + rr];
                gexF[rr * 9 + b] = s;
            }
            // tok flow control for hq_ts depth-4 ring (backoff kept; rarely waits)
            if (role == 0 && t >= 4 && tid == 0) {
                u64t* fp = hq_st + (size_t)(t & 1) * 16384 + gbase;
                u64t v = __hip_atomic_load(fp, __ATOMIC_RELAXED, __HIP_MEMORY_SCOPE_AGENT);
                while ((int)(v >> 32) < t - 3) {
                    __builtin_amdgcn_s_sleep(1);
                    v = __hip_atomic_load(fp, __ATOMIC_RELAXED, __HIP_MEMORY_SCOPE_AGENT);
                }
            }
            __syncthreads();
            // update + publish
            if (tid < 128) {
                const int q = tid >> 3, b2 = tid & 7;   // q in [0,16): h-pair
                const int jl0 = q << 1;
                float hn[2];
                #pragma unroll
                for (int u = 0; u < 2; ++u) {
                    const int j = jl0 + u;
                    const float gi = gexF[j * 9 + b2], gf = gexF[(32 + j) * 9 + b2];
                    const float gg = gexF[(64 + j) * 9 + b2], go = gexF[(96 + j) * 9 + b2];
                    const float cn = sigf(gf) * creg[u] + sigf(gi) * tanhf(gg);
                    hn[u] = sigf(go) * tanhf(cn);
                    creg[u] = cn;
                }
                const int bg = (g << 3) + b2;
                h16x2 hp2; hp2[0] = (h16)hn[0]; hp2[1] = (h16)hn[1];
                const u64t word = ((u64t)(unsigned)(t + 1) << 32) | __builtin_bit_cast(unsigned, hp2);
                const size_t woff = ((size_t)bg << 8) + (jb << 4) + q;
                __hip_atomic_store(hq + (size_t)(t & 1) * 16384 + woff,
                                   word, __ATOMIC_RELAXED, __HIP_MEMORY_SCOPE_AGENT);
                if (role == 0) {
                    __hip_atomic_store(hq_ts + (size_t)(t & 3) * 16384 + woff,
                                       word, __ATOMIC_RELAXED, __HIP_MEMORY_SCOPE_AGENT);
                }
                h16* rec = role ? (harec + (size_t)t * BH) : (tokrec + (size_t)t * BH);
                *(h16x2*)(rec + (size_t)bg * nH + (jb << 5) + jl0) = hp2;
            }
        }
    } else {
        // ---------------- st (role 2) ----------------
        const int sub = blk - 256;
        const int g = sub & 7, jb = sub >> 3;   // XCD-local: group g on XCD g
        const int kg = tid >> 5;             // [0,16) k-slice of 32; 2 per wave (free)
        const int rp = tid & 31;             // row-pair: rows 2rp,2rp+1 in [0,64)
        const int r0 = rp << 1;
        const int grow0 = (r0 >> 4) * nH + (jb << 4) + (r0 & 15);
        const int rr = tid & 63, bR = tid >> 6;      // reduce mapping
        const int growR = (rr >> 4) * nH + (jb << 4) + (rr & 15);
        h16x8 wa0[4], wa1[4], wb0[4], wb1[4];
        {
            const h16* a0p = sWhh16 + (size_t)grow0 * nH + (kg << 5);
            const h16* b0p = sWih16 + (size_t)grow0 * nH + (kg << 5);
            #pragma unroll
            for (int i = 0; i < 4; ++i) {
                wa0[i] = *(const h16x8*)(a0p + (i << 3));
                wa1[i] = *(const h16x8*)(a0p + nH + (i << 3));
                wb0[i] = *(const h16x8*)(b0p + (i << 3));
                wb1[i] = *(const h16x8*)(b0p + nH + (i << 3));
            }
            #pragma unroll
            for (int i = 0; i < 4; ++i) { PINV(wa0[i]); PINV(wa1[i]); PINV(wb0[i]); PINV(wb1[i]); }
        }
        const float gbias = sbias[growR];
        float creg[2] = {0.0f, 0.0f};
        const size_t gbase = (size_t)g << 11;
        for (int t = 0; t < nAc; ++t) {
            // own-chain h (sth[t-1]) -> hsmS (busy-poll)
            if (t == 0) {
                ((uint4*)hsmS)[tid] = make_uint4(0u, 0u, 0u, 0u);
            } else {
                const int want = t;
                u64t* base = hq_st + (size_t)((t - 1) & 1) * 16384 + gbase;
                u64t v[4];
                #pragma unroll
                for (int i = 0; i < 4; ++i)
                    v[i] = __hip_atomic_load(base + tid + (i << 9), __ATOMIC_RELAXED, __HIP_MEMORY_SCOPE_AGENT);
                #pragma unroll
                for (int i = 0; i < 4; ++i) {
                    while ((int)(v[i] >> 32) != want)
                        v[i] = __hip_atomic_load(base + tid + (i << 9), __ATOMIC_RELAXED, __HIP_MEMORY_SCOPE_AGENT);
                    ((unsigned*)hsmS)[tid + (i << 9)] = (unsigned)v[i];
                }
            }
            // tok h[t] + P1[t] -> hsmT (st_in), from depth-4 ring hq_ts (busy-poll)
            {
                const int want = t + 1;
                u64t* base = hq_ts + (size_t)(t & 3) * 16384 + gbase;
                const unsigned* p1p = (const unsigned*)(P1h + (size_t)t * BH) + (g << 11);
                u64t v[4];
                #pragma unroll
                for (int i = 0; i < 4; ++i)
                    v[i] = __hip_atomic_load(base + tid + (i << 9), __ATOMIC_RELAXED, __HIP_MEMORY_SCOPE_AGENT);
                #pragma unroll
                for (int i = 0; i < 4; ++i) {
                    while ((int)(v[i] >> 32) != want)
                        v[i] = __hip_atomic_load(base + tid + (i << 9), __ATOMIC_RELAXED, __HIP_MEMORY_SCOPE_AGENT);
                    const h16x2 tv = __builtin_bit_cast(h16x2, (unsigned)v[i]);
                    const h16x2 pv = __builtin_bit_cast(h16x2, p1p[tid + (i << 9)]);
                    h16x2 sum; sum[0] = tv[0] + pv[0]; sum[1] = tv[1] + pv[1];
                    ((unsigned*)hsmT)[tid + (i << 9)] = __builtin_bit_cast(unsigned, sum);
                }
            }
            __syncthreads();
            // partial sums: dual dot, each read feeds 2 rows
            __builtin_amdgcn_s_setprio(1);
            float acc0[8] = {0,0,0,0,0,0,0,0}, acc1[8] = {0,0,0,0,0,0,0,0};
            #pragma unroll
            for (int i = 0; i < 4; ++i) {
                const h16x2* pa0 = (const h16x2*)&wa0[i];
                const h16x2* pa1 = (const h16x2*)&wa1[i];
                const h16x2* pb0 = (const h16x2*)&wb0[i];
                const h16x2* pb1 = (const h16x2*)&wb1[i];
                #pragma unroll
                for (int b = 0; b < 8; ++b) {
                    h16x8 hs = *(const h16x8*)(&hsmS[b][(kg << 5) + (i << 3)]);
                    h16x8 ht = *(const h16x8*)(&hsmT[b][(kg << 5) + (i << 3)]);
                    const h16x2* hps = (const h16x2*)&hs;
                    const h16x2* hpt = (const h16x2*)&ht;
                    #pragma unroll
                    for (int p = 0; p < 4; ++p) {
                        acc0[b] = FDOT2(hps[p], pa0[p], acc0[b]);
                        acc0[b] = FDOT2(hpt[p], pb0[p], acc0[b]);
                        acc1[b] = FDOT2(hps[p], pa1[p], acc1[b]);
                        acc1[b] = FDOT2(hpt[p], pb1[p], acc1[b]);
                    }
                }
            }
            __builtin_amdgcn_s_setprio(0);
            #pragma unroll
            for (int b = 0; b < 8; ++b) {
                float2 pv; pv.x = acc0[b]; pv.y = acc1[b];
                *(float2*)&psF[(((kg << 3) + b) << 6) + r0] = pv;
            }
            __syncthreads();
            // reduce: thread handles (rr = tid&63, bR = tid>>6)
            {
                float s = gbias;
                #pragma unroll
                for (int k2 = 0; k2 < 16; ++k2) s += psF[(((k2 << 3) + bR) << 6) + rr];
                gexF[rr * 9 + bR] = s;
            }
            __syncthreads();
            if (tid < 64) {
                const int q = tid >> 3, b2 = tid & 7;   // q in [0,8)
                const int jl0 = q << 1;
                float hn[2];
                #pragma unroll
                for (int u = 0; u < 2; ++u) {
                    const int j = jl0 + u;
                    const float gi = gexF[j * 9 + b2], gf = gexF[(16 + j) * 9 + b2];
                    const float gg = gexF[(32 + j) * 9 + b2], go = gexF[(48 + j) * 9 + b2];
                    const float cn = sigf(gf) * creg[u] + sigf(gi) * tanhf(gg);
                    hn[u] = sigf(go) * tanhf(cn);
                    creg[u] = cn;
                }
                const int bg = (g << 3) + b2;
                h16x2 hp2; hp2[0] = (h16)hn[0]; hp2[1] = (h16)hn[1];
                const u64t word = ((u64t)(unsigned)(t + 1) << 32) | __builtin_bit_cast(unsigned, hp2);
                __hip_atomic_store(hq_st + (size_t)(t & 1) * 16384 + ((size_t)bg << 8) + (jb << 3) + q,
                                   word, __ATOMIC_RELAXED, __HIP_MEMORY_SCOPE_AGENT);
                *(h16x2*)(hsrec + (size_t)(t + 2) * BH + (size_t)bg * nH + (jb << 4) + jl0) = hp2;
            }
        }
    }
}

// ---------------- per-(t,b) logits + log-softmax loss ----------------
__global__ __launch_bounds__(128)
void loss_k(const h16* __restrict__ hidden, const float* __restrict__ f2aW,
            const float* __restrict__ f2ab, const int* __restrict__ actb,
            float* __restrict__ losses)
{
    const int r = blockIdx.x;
    const int t = r >> 6, b = r & 63;
    __shared__ __align__(16) float hrow[nH];
    __shared__ float lg[nNA + 1];
    const int tid = threadIdx.x;
    if (tid < 64) {
        const h16x8 v = ((const h16x8*)(hidden + (size_t)r * nH))[tid];
        #pragma unroll
        for (int j = 0; j < 8; ++j) hrow[tid * 8 + j] = (float)v[j];
    }
    __syncthreads();
    if (tid < nNA) {
        const float* wr = f2aW + (size_t)tid * nH;
        float a = f2ab[tid];
        for (int k = 0; k < nH; k += 4) {
            const float4 wv = *(const float4*)(wr + k);
            const float4 hv = *(const float4*)(&hrow[k]);
            a = fmaf(wv.x, hv.x, a); a = fmaf(wv.y, hv.y, a);
            a = fmaf(wv.z, hv.z, a); a = fmaf(wv.w, hv.w, a);
        }
        lg[tid] = a;
    }
    __syncthreads();
    if (tid < 64) {
        float m = -1e30f;
        for (int i = tid; i < nNA; i += 64) m = fmaxf(m, lg[i]);
        #pragma unroll
        for (int o = 32; o > 0; o >>= 1) m = fmaxf(m, __shfl_xor(m, o));
        float s = 0.0f;
        for (int i = tid; i < nNA; i += 64) s += __expf(lg[i] - m);
        #pragma unroll
        for (int o = 32; o > 0; o >>= 1) s += __shfl_xor(s, o);
        if (tid == 0) {
            const int a = actb[b * nAc + t];
            losses[r] = m + logf(s) - lg[a];
        }
    }
}

__global__ __launch_bounds__(256)
void reduce_k(const float* __restrict__ losses, float* __restrict__ out)
{
    __shared__ float sm[256];
    const int tid = threadIdx.x;
    float a = 0.0f;
    for (int i = tid; i < nS * nB; i += 256) a += losses[i];
    sm[tid] = a; __syncthreads();
    for (int s = 128; s > 0; s >>= 1) { if (tid < s) sm[tid] += sm[tid + s]; __syncthreads(); }
    if (tid == 0) out[0] = sm[0] * (1.0f / 16384.0f);
}

// ---------------- launch ----------------
extern "C" void kernel_launch(void* const* d_in, const int* in_sizes, int n_in,
                              void* d_out, int out_size, void* d_ws, size_t ws_size,
                              hipStream_t stream)
{
    const int*   tokb  = (const int*)  d_in[0];
    const int*   posb  = (const int*)  d_in[1];
    const int*   actb  = (const int*)  d_in[3];
    const float* wemb  = (const float*)d_in[4];
    const float* pemb  = (const float*)d_in[5];
    const float* aemb  = (const float*)d_in[6];
    const float* tWih  = (const float*)d_in[7];
    const float* tWhh  = (const float*)d_in[8];
    const float* tb    = (const float*)d_in[9];
    const float* sWih  = (const float*)d_in[10];
    const float* sWhh  = (const float*)d_in[11];
    const float* sb    = (const float*)d_in[12];
    const float* aWih  = (const float*)d_in[13];
    const float* aWhh  = (const float*)d_in[14];
    const float* ab    = (const float*)d_in[15];
    const float* redW  = (const float*)d_in[16];
    const float* redb  = (const float*)d_in[17];
    const float* compW = (const float*)d_in[18];
    const float* compb = (const float*)d_in[19];
    const float* h2fW  = (const float*)d_in[20];
    const float* h2fb  = (const float*)d_in[21];
    const float* f2aW  = (const float*)d_in[22];
    const float* f2ab  = (const float*)d_in[23];

    // ---- workspace carve ----
    char* base = (char*)d_ws;
    auto carve = [&](size_t bytes) { char* p = base; base += (bytes + 255) & ~(size_t)255; return p; };
    h16*   tok    = (h16*)  carve((size_t)nB * nS * nWD * 2);
    h16*   Xh     = (h16*)  carve((size_t)nS * nB * nG * 2);       // tokX (gx for tok chain), then hidden
    h16*   comph  = (h16*)  carve((size_t)nS * nB * nWD * 2);
    h16*   P1h    = (h16*)  carve((size_t)nS * BH * 2);            // composed@compW+compb
    h16*   tokrec = (h16*)  carve((size_t)nS * BH * 2);
    h16*   hsrec  = (h16*)  carve((size_t)(nS + 2) * BH * 2);
    h16*   harec  = (h16*)  carve((size_t)nS * BH * 2);
    h16*   tW16   = (h16*)  carve((size_t)nG * nH * 2);
    h16*   sW16   = (h16*)  carve((size_t)nG * nH * 2);
    h16*   aW16   = (h16*)  carve((size_t)nG * nH * 2);
    h16*   tWih16 = (h16*)  carve((size_t)nG * nWD * 2);
    h16*   sWih16 = (h16*)  carve((size_t)nG * nH * 2);
    h16*   h2f16  = (h16*)  carve((size_t)nH * nFH * 2);
    h16*   comp16 = (h16*)  carve((size_t)nH * nWD * 2);
    float* acTab  = (float*)carve((size_t)nNA * nG * 4);
    u64t*  hbuf   = (u64t*) carve((size_t)2 * 16384 * 8);
    u64t*  spbuf  = (u64t*) carve((size_t)2 * 16384 * 8);
    u64t*  apbuf  = (u64t*) carve((size_t)2 * 16384 * 8);
    u64t*  tsbuf  = (u64t*) carve((size_t)4 * 16384 * 8);          // tok->st depth-4 ring
    float* losses = (float*)carve((size_t)nS * nB * 4);
    int*   lab      = (int*)carve((size_t)nS * nB * 4);
    int*   counts   = (int*)carve(nLB * 4);
    int*   offs     = (int*)carve((nLB + 1) * 4);
    int*   fill     = (int*)carve(nLB * 4);
    int*   tl_lab   = (int*)carve(320 * 4);
    int*   tl_start = (int*)carve(320 * 4);
    int*   tl_cnt   = (int*)carve(320 * 4);
    int*   ntiles   = (int*)carve(4);
    int*   idxb     = (int*)carve((size_t)nS * nB * 4);

    init_k<<<dim3(256), dim3(256), 0, stream>>>(hsrec, counts, fill, hbuf, spbuf, apbuf, tsbuf);
    embed_k<<<dim3(nB * nS), dim3(64), 0, stream>>>(tokb, posb, wemb, pemb, tok);
    actab_k<<<dim3(nNA), dim3(256), 0, stream>>>(aemb, aWih, ab, acTab);
    cvt_k<<<dim3(1024), dim3(256), 0, stream>>>(tWhh, tW16, 262144);
    cvt_k<<<dim3(1024), dim3(256), 0, stream>>>(sWhh, sW16, 262144);
    cvt_k<<<dim3(1024), dim3(256), 0, stream>>>(aWhh, aW16, 262144);
    cvt_k<<<dim3(640),  dim3(256), 0, stream>>>(tWih, tWih16, 163840);
    cvt_k<<<dim3(1024), dim3(256), 0, stream>>>(sWih, sWih16, 262144);
    cvt_k<<<dim3(1280), dim3(256), 0, stream>>>(h2fW, h2f16, 327680);
    cvt_k<<<dim3(160),  dim3(256), 0, stream>>>(compW, comp16, 40960);
    // tokX = tok @ tok_Wih.T + tok_b -> Xh (MFMA)
    mgemm_k<0,false><<<dim3(256, 32), dim3(256), 0, stream>>>(tWih16, tb, tok, nullptr, nullptr, Xh, nWD, nG);
    hist_k<<<dim3(64), dim3(256), 0, stream>>>(actb, lab, counts);
    tiles_k<<<dim3(1), dim3(64), 0, stream>>>(counts, offs, tl_lab, tl_start, tl_cnt, ntiles);
    scatter_k<<<dim3(64), dim3(256), 0, stream>>>(lab, offs, fill, idxb);
    comp_gemm_k<<<dim3(304, 5), dim3(256), 0, stream>>>(tok, redW, redb, idxb, tl_lab, tl_start, tl_cnt, ntiles, comph);
    // P1 = composed @ comp_W.T + comp_b (MFMA, MODE 5)
    mgemm_k<5,false><<<dim3(256, 8), dim3(256), 0, stream>>>(comp16, compb, comph, nullptr, nullptr, P1h, nWD, nH);
    // fused pipelined scan: tok + ac + st (XCD-local groups, busy-poll)
    {
        const h16* a0 = tW16; const h16* a1 = sW16; const h16* a2 = sWih16; const h16* a3 = aW16;
        const h16* a4 = Xh; const float* a5 = acTab; const int* a6 = actb;
        const h16* a7 = P1h; const float* a8 = sb;
        u64t* a9 = hbuf; u64t* a10 = spbuf; u64t* a11 = apbuf; u64t* a12 = tsbuf;
        h16* a13 = tokrec; h16* a14 = hsrec; h16* a15 = harec;
        void* args[] = {&a0, &a1, &a2, &a3, &a4, &a5, &a6, &a7, &a8, &a9, &a10, &a11, &a12, &a13, &a14, &a15};
        hipLaunchCooperativeKernel((const void*)fused_scan_k, dim3(512), dim3(512), args, 0, stream);
    }
    // hidden = relu(feat @ h2f_W.T + h2f_b) -> Xh (MFMA)
    mgemm_k<3,true><<<dim3(256, 8), dim3(256), 0, stream>>>(h2f16, h2fb, hsrec, tokrec, harec, Xh, nFH, nH);
    loss_k<<<dim3(nS * nB), dim3(128), 0, stream>>>(Xh, f2aW, f2ab, actb, losses);
    reduce_k<<<dim3(1), dim3(256), 0, stream>>>(losses, (float*)d_out);
}